// Round 7
// baseline (77.087 us; speedup 1.0000x reference)
//
#include <hip/hip_runtime.h>

// FullAttention_Spatial: N=4, L=S=1024, H=16, E=D=64, NUM_POS=2, fp32 in/out.
//
// score = temp*(QK + attn_mask[l,s] + klm[n,s]) + pos_table[pos[n,l,s]][h]
// pos in {0,1} => bias = T0[h] + bit*(T1[h]-T0[h]); T0 cancels in softmax.
// Log2-domain softmax; Q pre-scaled by temp2 = temp*log2e.
//
// R6: NO LDS, NO barriers. K/V prepacked in MFMA-fragment order so each
// fragment is one coalesced 1KB global_load_dwordx4 per wave (L2-resident:
// 8 panels x 256KB = 2MB per XCD via bid%8 = (n*16+h)%8 affinity).
// Single-wave blocks (64 thr), grid 2048. Cross-tile pipeline kept:
// body(T) = {QK(T) || PV(T-1) interleaved w/ next-frag loads; bias+softmax;
// pack P in-register (plswap)}. Loads issued right after their consumer
// MFMA -> ~1 body of latency slack, counted by compiler vmcnt.
//
// Fragment layouts (shorts, per (n,h) panel of 65536):
//  Kp: ((t*4+ks)*2+sh)*512 + (h5*32+s31)*8  holds K[s=t*64+sh*32+s31][e=ks*16+h5*8+j]
//  Vt: ((t*4+ks)*2+dh)*512 + (h5*32+d31)*8  holds V^T[d=dh*32+d31][s=t*64+ks*16+h5*8+j]
// MFMA 32x32x16: C col=lane&31, row=(reg&3)+8*(reg>>2)+4*(lane>>5);
// A row=lane&31, k=8*(lane>>5)+j; B col=lane&31, k=8*(lane>>5)+j.

typedef __attribute__((ext_vector_type(8))) __bf16 bf16x8;
typedef __attribute__((ext_vector_type(16))) float f32x16;
typedef __attribute__((ext_vector_type(4))) unsigned int u32x4;

#define TEMP2 (0.125f * 1.4426950408889634f)
#define LG2E 1.4426950408889634f

static __device__ __forceinline__ unsigned short f2bf(float x) {
  unsigned int u = __builtin_bit_cast(unsigned int, x);
  u += 0x7FFFu + ((u >> 16) & 1u);
  return (unsigned short)(u >> 16);
}
static __device__ __forceinline__ unsigned int cvtpk(float lo, float hi) {
  unsigned int r;
  asm("v_cvt_pk_bf16_f32 %0, %1, %2" : "=v"(r) : "v"(lo), "v"(hi));
  return r;
}
// After: a = {a.lo32, b.lo32}, b = {a.hi32, b.hi32}
static __device__ __forceinline__ void plswap(unsigned int& a, unsigned int& b) {
  asm("v_permlane32_swap_b32 %0, %1" : "+v"(a), "+v"(b));
}

// ---------------- fused prepass ----------------
__global__ __launch_bounds__(256) void k_prep(
    const int* __restrict__ pos, unsigned int* __restrict__ pospk,
    const float* __restrict__ K, unsigned short* __restrict__ Kp,
    const float* __restrict__ V, unsigned short* __restrict__ Vt,
    const float* __restrict__ mask, const float* __restrict__ klm,
    unsigned short* __restrict__ CM, int use_cm) {
  __shared__ float ld[64][65];
  int b = blockIdx.x;
  int tid = threadIdx.x;
  if (b < 256) {
    // ---- K -> fragment order ----
    int idx = b * 256 + tid;           // ((n*1024+s)*16+h)
    int s = (idx >> 4) & 1023;
    const float* src = K + idx * 64;
    unsigned short row[64];
#pragma unroll
    for (int j = 0; j < 16; ++j) {
      float4 v = *(const float4*)(src + j * 4);
      row[j*4+0] = f2bf(v.x); row[j*4+1] = f2bf(v.y);
      row[j*4+2] = f2bf(v.z); row[j*4+3] = f2bf(v.w);
    }
    int n = idx >> 14, h = idx & 15;
    unsigned short* panel = Kp + (n * 16 + h) * 65536;
    int t = s >> 6, sh = (s >> 5) & 1, s31 = s & 31;
#pragma unroll
    for (int bb = 0; bb < 8; ++bb) {
      int ks = bb >> 1, hf = bb & 1;
      int off = ((t * 4 + ks) * 2 + sh) * 512 + (hf * 32 + s31) * 8;
      *(u32x4*)(panel + off) = *(const u32x4*)(&row[bb * 8]);
    }
  } else if (b < 1280) {
    // ---- V transpose -> fragment order ----
    int vb = b - 256;
    int t = vb & 15, h = (vb >> 4) & 15, n = vb >> 8;
    {
      int s = tid >> 2, dq = (tid & 3) * 16;
      const float* src = V + ((n * 1024 + t * 64 + s) * 16 + h) * 64 + dq;
#pragma unroll
      for (int j = 0; j < 4; ++j) {
        float4 v = *(const float4*)(src + j * 4);
        ld[s][dq + j*4 + 0] = v.x; ld[s][dq + j*4 + 1] = v.y;
        ld[s][dq + j*4 + 2] = v.z; ld[s][dq + j*4 + 3] = v.w;
      }
    }
    __syncthreads();
    {
      int d = tid >> 2, sq = (tid & 3) * 16;
      unsigned short vals[16];
#pragma unroll
      for (int k = 0; k < 16; ++k) vals[k] = f2bf(ld[sq + k][d]);
      unsigned short* panel = Vt + (n * 16 + h) * 65536;
      int dh = d >> 5, d31 = d & 31;
#pragma unroll
      for (int cb = 0; cb < 2; ++cb) {
        int sl = sq + cb * 8;
        int ks = sl >> 4, hf = (sl >> 3) & 1;
        int off = ((t * 4 + ks) * 2 + dh) * 512 + (hf * 32 + d31) * 8;
        *(u32x4*)(panel + off) = *(const u32x4*)(&vals[cb * 8]);
      }
    }
  } else if (b < 2304) {
    // ---- combined mask (bf16, pre-scaled) ----
    if (!use_cm) return;
    int flat = (b - 1280) * 256 * 16 + tid * 16;
    int n = flat >> 20, l = (flat >> 10) & 1023, s0 = flat & 1023;
    const float* mrow = mask + l * 1024 + s0;
    const float* krow = klm + n * 1024 + s0;
    unsigned int o[8];
#pragma unroll
    for (int j = 0; j < 4; ++j) {
      float4 mv = *(const float4*)(mrow + j * 4);
      float4 kv = *(const float4*)(krow + j * 4);
      o[j*2+0] = cvtpk((mv.x + kv.x) * TEMP2, (mv.y + kv.y) * TEMP2);
      o[j*2+1] = cvtpk((mv.z + kv.z) * TEMP2, (mv.w + kv.w) * TEMP2);
    }
    *(u32x4*)(CM + flat)     = *(const u32x4*)(&o[0]);
    *(u32x4*)(CM + flat + 8) = *(const u32x4*)(&o[4]);
  } else {
    // ---- pack pos bits ----
    int gi = (b - 2304) * 256 + tid;
    int v = pos[gi];
    unsigned long long m = __ballot(v & 1);
    int lane = tid & 63;
    if (lane == 0) pospk[gi >> 5] = (unsigned int)m;
    else if (lane == 32) pospk[gi >> 5] = (unsigned int)(m >> 32);
  }
}

// ---------------- main flash-attention kernel ----------------
// grid 2048 = lblk*64 + n*16 + h ; ONE wave (64 thr), 32 q-rows.
template <bool USE_CM>
__global__ __launch_bounds__(64, 2) void k_attn(
    const float* __restrict__ Q, const float* __restrict__ mask,
    const float* __restrict__ klm, const float* __restrict__ ptab,
    const unsigned int* __restrict__ pospk,
    const unsigned short* __restrict__ Kp, const unsigned short* __restrict__ Vt,
    const unsigned short* __restrict__ CMp,
    float* __restrict__ out) {
  int bid = blockIdx.x;
  int nh = bid & 63;
  int n = nh >> 4, h = nh & 15, lblk = bid >> 6;
  int lane = threadIdx.x & 63;
  int l31 = lane & 31, h5 = lane >> 5;
  int l = lblk * 32 + l31;             // this lane's q-row (global)
  const int ln8 = lane * 8;

  // Q fragments (B of swapped QK^T), pre-scaled by temp2
  const float* qrow = Q + ((n * 1024 + l) * 16 + h) * 64;
  bf16x8 qf[4];
#pragma unroll
  for (int ke = 0; ke < 4; ++ke) {
    float4 a = *(const float4*)(qrow + ke * 16 + h5 * 8);
    float4 bq = *(const float4*)(qrow + ke * 16 + h5 * 8 + 4);
    u32x4 pk;
    pk[0] = cvtpk(a.x * TEMP2, a.y * TEMP2);
    pk[1] = cvtpk(a.z * TEMP2, a.w * TEMP2);
    pk[2] = cvtpk(bq.x * TEMP2, bq.y * TEMP2);
    pk[3] = cvtpk(bq.z * TEMP2, bq.w * TEMP2);
    qf[ke] = __builtin_bit_cast(bf16x8, pk);
  }
  const float delta2 = (ptab[16 + h] - ptab[h]) * LG2E;

  float mrun = -1e30f, lrun = 0.f;
  f32x16 Oc0 = {0,0,0,0,0,0,0,0,0,0,0,0,0,0,0,0};
  f32x16 Oc1 = {0,0,0,0,0,0,0,0,0,0,0,0,0,0,0,0};
  u32x4 pfA = {0,0,0,0}, pfB = {0,0,0,0}, pfC = {0,0,0,0}, pfD = {0,0,0,0};
  u32x4 kf[2][4], vf[2][4];

  const unsigned short* KpB = Kp + nh * 65536;
  const unsigned short* VtB = Vt + nh * 65536;
  const unsigned short* CMb = USE_CM ? (CMp + (n * 1024 + l) * 1024) : nullptr;
  const float* mrowB = mask + l * 1024;
  const float* krowB = klm + n * 1024;
  const unsigned int* posB = pospk + (n * 1024 + l) * 32;
  const int h4 = h5 * 4;

#define BF(x) __builtin_bit_cast(bf16x8, x)
#define MFMA(A, B, C) __builtin_amdgcn_mfma_f32_32x32x16_bf16(A, B, C, 0, 0, 0)

  // ---- prologue: K-frags tile 0; pos/bias tile 0 ----
  {
    const unsigned short* k0 = KpB + ln8;
#pragma unroll
    for (int ks = 0; ks < 4; ++ks) {
      kf[0][ks] = *(const u32x4*)(k0 + (ks * 2 + 0) * 512);
      kf[1][ks] = *(const u32x4*)(k0 + (ks * 2 + 1) * 512);
    }
  }
  uint2 pwv = *(const uint2*)(posB);
  uint2 cmq[8];
  if constexpr (USE_CM) {
#pragma unroll
    for (int q8 = 0; q8 < 8; ++q8)
      cmq[q8] = *(const uint2*)(CMb + (q8 >> 2) * 32 + (q8 & 3) * 8 + h4);
  }

#define BODY(T, DO_PV, STG)                                                    \
  {                                                                            \
    uint2 npwv = {0, 0};                                                       \
    uint2 ncmq[8];                                                             \
    if (STG) {                                                                 \
      npwv = *(const uint2*)(posB + ((T) + 1) * 2);                            \
      if constexpr (USE_CM) {                                                  \
        _Pragma("unroll")                                                      \
        for (int q8 = 0; q8 < 8; ++q8)                                         \
          ncmq[q8] = *(const uint2*)(CMb + ((T) + 1) * 64 + (q8 >> 2) * 32 +   \
                                     (q8 & 3) * 8 + h4);                       \
      }                                                                        \
    }                                                                          \
    const unsigned short* kN = KpB + ((T) + 1) * 4096 + ln8;                   \
    const unsigned short* vC = VtB + (T) * 4096 + ln8;                         \
    f32x16 sv0 = {0,0,0,0,0,0,0,0,0,0,0,0,0,0,0,0};                            \
    f32x16 sv1 = {0,0,0,0,0,0,0,0,0,0,0,0,0,0,0,0};                            \
    /* ---- MFMA block: QK(T) || PV(T-1); reload frags right after use ---- */ \
    __builtin_amdgcn_s_setprio(1);                                             \
    sv0 = MFMA(BF(kf[0][0]), qf[0], sv0);                                      \
    sv1 = MFMA(BF(kf[1][0]), qf[0], sv1);                                      \
    if (DO_PV) {                                                               \
      Oc0 = MFMA(BF(vf[0][0]), BF(pfA), Oc0);                                  \
      Oc1 = MFMA(BF(vf[1][0]), BF(pfA), Oc1);                                  \
    }                                                                          \
    if (STG) {                                                                 \
      kf[0][0] = *(const u32x4*)(kN + 0 * 512);                                \
      kf[1][0] = *(const u32x4*)(kN + 1 * 512);                                \
    }                                                                          \
    vf[0][0] = *(const u32x4*)(vC + 0 * 512);                                  \
    vf[1][0] = *(const u32x4*)(vC + 1 * 512);                                  \
    sv0 = MFMA(BF(kf[0][1]), qf[1], sv0);                                      \
    sv1 = MFMA(BF(kf[1][1]), qf[1], sv1);                                      \
    if (DO_PV) {                                                               \
      Oc0 = MFMA(BF(vf[0][1]), BF(pfB), Oc0);                                  \
      Oc1 = MFMA(BF(vf[1][1]), BF(pfB), Oc1);                                  \
    }                                                                          \
    if (STG) {                                                                 \
      kf[0][1] = *(const u32x4*)(kN + 2 * 512);                                \
      kf[1][1] = *(const u32x4*)(kN + 3 * 512);                                \
    }                                                                          \
    vf[0][1] = *(const u32x4*)(vC + 2 * 512);                                  \
    vf[1][1] = *(const u32x4*)(vC + 3 * 512);                                  \
    sv0 = MFMA(BF(kf[0][2]), qf[2], sv0);                                      \
    sv1 = MFMA(BF(kf[1][2]), qf[2], sv1);                                      \
    if (DO_PV) {                                                               \
      Oc0 = MFMA(BF(vf[0][2]), BF(pfC), Oc0);                                  \
      Oc1 = MFMA(BF(vf[1][2]), BF(pfC), Oc1);                                  \
    }                                                                          \
    if (STG) {                                                                 \
      kf[0][2] = *(const u32x4*)(kN + 4 * 512);                                \
      kf[1][2] = *(const u32x4*)(kN + 5 * 512);                                \
    }                                                                          \
    vf[0][2] = *(const u32x4*)(vC + 4 * 512);                                  \
    vf[1][2] = *(const u32x4*)(vC + 5 * 512);                                  \
    sv0 = MFMA(BF(kf[0][3]), qf[3], sv0);                                      \
    sv1 = MFMA(BF(kf[1][3]), qf[3], sv1);                                      \
    if (DO_PV) {                                                               \
      Oc0 = MFMA(BF(vf[0][3]), BF(pfD), Oc0);                                  \
      Oc1 = MFMA(BF(vf[1][3]), BF(pfD), Oc1);                                  \
    }                                                                          \
    if (STG) {                                                                 \
      kf[0][3] = *(const u32x4*)(kN + 6 * 512);                                \
      kf[1][3] = *(const u32x4*)(kN + 7 * 512);                                \
    }                                                                          \
    vf[0][3] = *(const u32x4*)(vC + 6 * 512);                                  \
    vf[1][3] = *(const u32x4*)(vC + 7 * 512);                                  \
    __builtin_amdgcn_s_setprio(0);                                             \
    /* ---- bias: CM + pos bit, s=(i)+8*r2+4*h5 (+32 for sv1) ---- */          \
    {                                                                          \
      unsigned pws0 = pwv.x >> h4;                                             \
      unsigned pws1 = pwv.y >> h4;                                             \
      _Pragma("unroll")                                                        \
      for (int r2 = 0; r2 < 4; ++r2) {                                         \
        float b0[4], b1[4];                                                    \
        if constexpr (USE_CM) {                                                \
          b0[0] = __builtin_bit_cast(float, cmq[r2].x << 16);                  \
          b0[1] = __builtin_bit_cast(float, cmq[r2].x & 0xFFFF0000u);          \
          b0[2] = __builtin_bit_cast(float, cmq[r2].y << 16);                  \
          b0[3] = __builtin_bit_cast(float, cmq[r2].y & 0xFFFF0000u);          \
          b1[0] = __builtin_bit_cast(float, cmq[4 + r2].x << 16);              \
          b1[1] = __builtin_bit_cast(float, cmq[4 + r2].x & 0xFFFF0000u);      \
          b1[2] = __builtin_bit_cast(float, cmq[4 + r2].y << 16);              \
          b1[3] = __builtin_bit_cast(float, cmq[4 + r2].y & 0xFFFF0000u);      \
        } else {                                                               \
          float4 mv0 = *(const float4*)(mrowB + (T) * 64 + r2 * 8 + h4);       \
          float4 kv0 = *(const float4*)(krowB + (T) * 64 + r2 * 8 + h4);       \
          float4 mv1 = *(const float4*)(mrowB + (T) * 64 + 32 + r2 * 8 + h4);  \
          float4 kv1 = *(const float4*)(krowB + (T) * 64 + 32 + r2 * 8 + h4);  \
          b0[0] = (mv0.x + kv0.x) * TEMP2; b0[1] = (mv0.y + kv0.y) * TEMP2;    \
          b0[2] = (mv0.z + kv0.z) * TEMP2; b0[3] = (mv0.w + kv0.w) * TEMP2;    \
          b1[0] = (mv1.x + kv1.x) * TEMP2; b1[1] = (mv1.y + kv1.y) * TEMP2;    \
          b1[2] = (mv1.z + kv1.z) * TEMP2; b1[3] = (mv1.w + kv1.w) * TEMP2;    \
        }                                                                      \
        _Pragma("unroll")                                                      \
        for (int i = 0; i < 4; ++i) {                                          \
          float bit0 = (float)((pws0 >> (r2 * 8 + i)) & 1u);                   \
          float bit1 = (float)((pws1 >> (r2 * 8 + i)) & 1u);                   \
          sv0[r2 * 4 + i] = fmaf(bit0, delta2, sv0[r2 * 4 + i] + b0[i]);       \
          sv1[r2 * 4 + i] = fmaf(bit1, delta2, sv1[r2 * 4 + i] + b1[i]);       \
        }                                                                      \
      }                                                                        \
    }                                                                          \
    /* ---- online softmax (row q: lanes l31, l31+32) ---- */                  \
    {                                                                          \
      float m8[8];                                                             \
      _Pragma("unroll")                                                        \
      for (int i = 0; i < 8; ++i)                                              \
        m8[i] = fmaxf(fmaxf(sv0[2 * i], sv0[2 * i + 1]),                       \
                      fmaxf(sv1[2 * i], sv1[2 * i + 1]));                      \
      float m4a = fmaxf(m8[0], m8[1]), m4b = fmaxf(m8[2], m8[3]);              \
      float m4c = fmaxf(m8[4], m8[5]), m4d = fmaxf(m8[6], m8[7]);              \
      float tmax = fmaxf(fmaxf(m4a, m4b), fmaxf(m4c, m4d));                    \
      tmax = fmaxf(tmax, __shfl_xor(tmax, 32));                                \
      if (!__all(tmax <= mrun + 4.0f)) {                                       \
        float mnew = fmaxf(mrun, tmax);                                        \
        float sc = __builtin_amdgcn_exp2f(mrun - mnew);                        \
        lrun *= sc;                                                            \
        Oc0 *= sc; Oc1 *= sc;                                                  \
        mrun = mnew;                                                           \
      }                                                                        \
      float s8[8];                                                             \
      _Pragma("unroll")                                                        \
      for (int i = 0; i < 8; ++i) {                                            \
        float p0 = __builtin_amdgcn_exp2f(sv0[2 * i] - mrun);                  \
        float p1 = __builtin_amdgcn_exp2f(sv0[2 * i + 1] - mrun);              \
        float p2 = __builtin_amdgcn_exp2f(sv1[2 * i] - mrun);                  \
        float p3 = __builtin_amdgcn_exp2f(sv1[2 * i + 1] - mrun);              \
        sv0[2 * i] = p0; sv0[2 * i + 1] = p1;                                  \
        sv1[2 * i] = p2; sv1[2 * i + 1] = p3;                                  \
        s8[i] = (p0 + p1) + (p2 + p3);                                         \
      }                                                                        \
      float s4a = s8[0] + s8[1], s4b = s8[2] + s8[3];                          \
      float s4c = s8[4] + s8[5], s4d = s8[6] + s8[7];                          \
      lrun += (s4a + s4b) + (s4c + s4d);   /* lane-partial; combined at end */ \
    }                                                                          \
    /* ---- pack P(T) -> pfA..pfD (pre-swapped B-frags) ---- */                \
    {                                                                          \
      unsigned a0 = cvtpk(sv0[0], sv0[1]),   a1 = cvtpk(sv0[2], sv0[3]);       \
      unsigned a2 = cvtpk(sv0[4], sv0[5]),   a3 = cvtpk(sv0[6], sv0[7]);       \
      plswap(a0, a2); plswap(a1, a3);                                          \
      pfA[0] = a0; pfA[1] = a1; pfA[2] = a2; pfA[3] = a3;                      \
      unsigned b0_ = cvtpk(sv0[8], sv0[9]),   b1_ = cvtpk(sv0[10], sv0[11]);   \
      unsigned b2_ = cvtpk(sv0[12], sv0[13]), b3_ = cvtpk(sv0[14], sv0[15]);   \
      plswap(b0_, b2_); plswap(b1_, b3_);                                      \
      pfB[0] = b0_; pfB[1] = b1_; pfB[2] = b2_; pfB[3] = b3_;                  \
      unsigned c0 = cvtpk(sv1[0], sv1[1]),   c1 = cvtpk(sv1[2], sv1[3]);       \
      unsigned c2 = cvtpk(sv1[4], sv1[5]),   c3 = cvtpk(sv1[6], sv1[7]);       \
      plswap(c0, c2); plswap(c1, c3);                                          \
      pfC[0] = c0; pfC[1] = c1; pfC[2] = c2; pfC[3] = c3;                      \
      unsigned d0 = cvtpk(sv1[8], sv1[9]),   d1 = cvtpk(sv1[10], sv1[11]);     \
      unsigned d2 = cvtpk(sv1[12], sv1[13]), d3 = cvtpk(sv1[14], sv1[15]);     \
      plswap(d0, d2); plswap(d1, d3);                                          \
      pfD[0] = d0; pfD[1] = d1; pfD[2] = d2; pfD[3] = d3;                      \
    }                                                                          \
    if (STG) {                                                                 \
      pwv = npwv;                                                              \
      if constexpr (USE_CM) {                                                  \
        _Pragma("unroll")                                                      \
        for (int q8 = 0; q8 < 8; ++q8) cmq[q8] = ncmq[q8];                     \
      }                                                                        \
    }                                                                          \
  }

  //     T  PV STG
  BODY( 0, 0, 1)
  BODY( 1, 1, 1)
  BODY( 2, 1, 1)
  BODY( 3, 1, 1)
  BODY( 4, 1, 1)
  BODY( 5, 1, 1)
  BODY( 6, 1, 1)
  BODY( 7, 1, 1)
  BODY( 8, 1, 1)
  BODY( 9, 1, 1)
  BODY(10, 1, 1)
  BODY(11, 1, 1)
  BODY(12, 1, 1)
  BODY(13, 1, 1)
  BODY(14, 1, 1)
  BODY(15, 1, 0)
#undef BODY

  // ---- epilogue PV(15): vf holds V(15) ----
  __builtin_amdgcn_s_setprio(1);
  Oc0 = MFMA(BF(vf[0][0]), BF(pfA), Oc0);
  Oc1 = MFMA(BF(vf[1][0]), BF(pfA), Oc1);
  Oc0 = MFMA(BF(vf[0][1]), BF(pfB), Oc0);
  Oc1 = MFMA(BF(vf[1][1]), BF(pfB), Oc1);
  Oc0 = MFMA(BF(vf[0][2]), BF(pfC), Oc0);
  Oc1 = MFMA(BF(vf[1][2]), BF(pfC), Oc1);
  Oc0 = MFMA(BF(vf[0][3]), BF(pfD), Oc0);
  Oc1 = MFMA(BF(vf[1][3]), BF(pfD), Oc1);
  __builtin_amdgcn_s_setprio(0);
#undef MFMA
#undef BF

  // ---- epilogue: combine lane-partial lrun, /l, store O^T ----
  lrun += __shfl_xor(lrun, 32);
  float inv = 1.0f / lrun;
  float* orow = out + ((n * 1024 + l) * 16 + h) * 64;
#pragma unroll
  for (int r2 = 0; r2 < 4; ++r2) {
    float4 o;
    o.x = Oc0[4 * r2 + 0] * inv; o.y = Oc0[4 * r2 + 1] * inv;
    o.z = Oc0[4 * r2 + 2] * inv; o.w = Oc0[4 * r2 + 3] * inv;
    *(float4*)(orow + r2 * 8 + h4) = o;
    o.x = Oc1[4 * r2 + 0] * inv; o.y = Oc1[4 * r2 + 1] * inv;
    o.z = Oc1[4 * r2 + 2] * inv; o.w = Oc1[4 * r2 + 3] * inv;
    *(float4*)(orow + 32 + r2 * 8 + h4) = o;
  }
}

extern "C" void kernel_launch(void* const* d_in, const int* in_sizes, int n_in,
                              void* d_out, int out_size, void* d_ws, size_t ws_size,
                              hipStream_t stream) {
  const float* Q    = (const float*)d_in[0];
  const float* K    = (const float*)d_in[1];
  const float* V    = (const float*)d_in[2];
  const float* mask = (const float*)d_in[3];
  const float* klm  = (const float*)d_in[4];
  const float* ptab = (const float*)d_in[5];
  const int*   pos  = (const int*)d_in[6];
  float* out = (float*)d_out;

  char* ws = (char*)d_ws;
  unsigned int*   pospk = (unsigned int*)ws;                               // 512 KB
  unsigned short* Kp    = (unsigned short*)(ws + (1 << 19));               // 8 MB
  unsigned short* Vt    = (unsigned short*)(ws + (1 << 19) + (8 << 20));   // 8 MB
  unsigned short* CM    = (unsigned short*)(ws + (1 << 19) + (16 << 20));  // 8 MB
  const size_t need_cm = (size_t)(1 << 19) + (size_t)(24 << 20);
  const bool use_cm = ws_size >= need_cm;

  k_prep<<<18688, 256, 0, stream>>>(pos, pospk, K, Kp, V, Vt, mask, klm, CM,
                                    use_cm ? 1 : 0);
  if (use_cm) {
    k_attn<true><<<2048, 64, 0, stream>>>(Q, mask, klm, ptab, pospk, Kp, Vt, CM, out);
  } else {
    k_attn<false><<<2048, 64, 0, stream>>>(Q, mask, klm, ptab, pospk, Kp, Vt, nullptr, out);
  }
}